// Round 2
// baseline (43.170 us; speedup 1.0000x reference)
//
#include <hip/hip_runtime.h>

#define N1 8192
#define N2 8192
#define KNN 32

// f32(0.1*0.1) -- the reference's weak-promoted threshold
#define R2_F32 0.009999999776482582f

__global__ __launch_bounds__(256) void ballq_kernel(
    const float* __restrict__ p1, const float* __restrict__ p2,
    float* __restrict__ map_f, float* __restrict__ cnt_f, float* __restrict__ out_f)
{
    const int q    = (int)((blockIdx.x * blockDim.x + threadIdx.x) >> 6); // one wave per query
    const int lane = (int)(threadIdx.x & 63);
    if (q >= N1) return;

    const float qx = p1[3 * q + 0];
    const float qy = p1[3 * q + 1];
    const float qz = p1[3 * q + 2];
    // s1 = (qx^2 + qy^2) + qz^2, numpy style: rounded products, sequential adds, no FMA
    const float s1 = __fadd_rn(__fadd_rn(__fmul_rn(qx, qx), __fmul_rn(qy, qy)),
                               __fmul_rn(qz, qz));

    int count = 0;
    const int base_map = q * KNN;

    for (int base = 0; base < N2; base += 64) {
        const int j = base + lane;
        const float px = p2[3 * j + 0];
        const float py = p2[3 * j + 1];
        const float pz = p2[3 * j + 2];

        // s2 = (px^2 + py^2) + pz^2, no FMA (numpy elementwise mul + sum)
        const float s2 = __fadd_rn(__fadd_rn(__fmul_rn(px, px), __fmul_rn(py, py)),
                                   __fmul_rn(pz, pz));
        // dot = BLAS sgemm K=3 microkernel: fma chain, k ascending
        const float dot = __fmaf_rn(qz, pz, __fmaf_rn(qy, py, __fmul_rn(qx, px)));
        // d2 = (s1 + s2) - 2*dot ; the *2 is exact (exponent bump)
        const float d2 = __fsub_rn(__fadd_rn(s1, s2), __fadd_rn(dot, dot));
        const bool within = (d2 <= R2_F32);

        const unsigned long long mask = __ballot(within);
        if (mask) {
            const int pos = count + (int)__popcll(mask & ((1ull << lane) - 1ull));
            if (within && pos < KNN) {
                map_f[base_map + pos] = (float)j;
                float* o = out_f + (size_t)(base_map + pos) * 3;
                o[0] = px; o[1] = py; o[2] = pz;
            }
            count += (int)__popcll(mask);
            if (count >= KNN) { count = KNN; break; }  // wave-uniform early exit
        }
    }

    // Zero-fill the padded tail (d_out poisoned 0xAA; every element must be written)
    if (lane < KNN - count) {
        const int s = base_map + count + lane;
        map_f[s] = 0.0f;
        float* o = out_f + (size_t)s * 3;
        o[0] = 0.0f; o[1] = 0.0f; o[2] = 0.0f;
    }
    if (lane == 0) cnt_f[q] = (float)count;
}

extern "C" void kernel_launch(void* const* d_in, const int* in_sizes, int n_in,
                              void* d_out, int out_size, void* d_ws, size_t ws_size,
                              hipStream_t stream) {
    const float* p1 = (const float*)d_in[0];  // [1, N1, 3] f32
    const float* p2 = (const float*)d_in[1];  // [1, N2, 3] f32
    float* out = (float*)d_out;

    float* map_f = out;                        // N1*KNN (mapping)
    float* cnt_f = out + (size_t)N1 * KNN;     // N1 (counts)
    float* out_f = cnt_f + N1;                 // N1*KNN*3 (gathered coords)

    dim3 block(256);
    dim3 grid(N1 / (256 / 64));  // one wave per query
    hipLaunchKernelGGL(ballq_kernel, grid, block, 0, stream,
                       p1, p2, map_f, cnt_f, out_f);
}